// Round 4
// baseline (429.971 us; speedup 1.0000x reference)
//
#include <hip/hip_runtime.h>
#include <stdint.h>

#define M_TOK 256
#define N_OUT 16384
#define K_IN  4096
#define BM 64
#define BN 128
#define BK 128
#define NSTEPS (K_IN / BK)   // 32

typedef short v8s __attribute__((ext_vector_type(8)));
typedef float v4f __attribute__((ext_vector_type(4)));
typedef int   v4i __attribute__((ext_vector_type(4)));
typedef unsigned int uint;

__device__ __forceinline__ uint bf16_trunc_bits(float f) {
  return __float_as_uint(f) >> 16;  // exact for integers |v| <= 256
}
__device__ __forceinline__ unsigned short rne_bf16(float f) {
  uint u = __float_as_uint(f);
  uint r = u + 0x7FFFu + ((u >> 16) & 1u);
  return (unsigned short)(r >> 16);
}
__device__ __forceinline__ float bfbits_to_f(uint h) {
  return __uint_as_float(h << 16);
}

// ---------------- kernel 1: exact dual-bf16 split of x ----------------
// x = hi + lo with hi = bf16_rne(x), lo = bf16_rne(x - hi); residual ~2^-18 |x|
__global__ __launch_bounds__(256) void cast_kernel(
    const float* __restrict__ x, unsigned short* __restrict__ xhi,
    unsigned short* __restrict__ xlo) {
  const int i = (blockIdx.x * 256 + threadIdx.x) * 4;
  const float4 f = *(const float4*)(x + i);
  float fs[4] = {f.x, f.y, f.z, f.w};
  unsigned short h[4], l[4];
#pragma unroll
  for (int j = 0; j < 4; ++j) {
    h[j] = rne_bf16(fs[j]);
    l[j] = rne_bf16(fs[j] - bfbits_to_f(h[j]));
  }
  *(ushort4*)(xhi + i) = make_ushort4(h[0], h[1], h[2], h[3]);
  *(ushort4*)(xlo + i) = make_ushort4(l[0], l[1], l[2], l[3]);
}

// ---------------- kernel 2: dual-plane bf16 MFMA GEMM, W dtype probed ----------------
// LDS (single buffer, 64 KiB): xhi 16K @0 | xlo 16K @16384 | W(bf16) 32K @32768
// Rows are 256B = 16 chunks of 16B; LDS[row r][pos p] = global chunk p^(r&15)
// -> every 8-lane phase of a ds_read_b128 covers a contiguous 128B half-row: conflict-free.
__global__ __launch_bounds__(256, 2) void gemm_kernel(
    const unsigned short* __restrict__ xhi, const unsigned short* __restrict__ xlo,
    const void* __restrict__ wraw, const float* __restrict__ scales,
    float* __restrict__ out) {
  __shared__ alignas(16) unsigned char smem[65536];
  const int tid = threadIdx.x;
  const int lane = tid & 63;
  const int wid = tid >> 6;

  // --- runtime dtype probe: 64B read, in-bounds under both layouts; uniform result
  const int* wi = (const int*)wraw;
  const signed char* wb = (const signed char*)wraw;
  bool is32 = true;
#pragma unroll
  for (int i = 0; i < 16; ++i) {
    const int v = wi[i];
    is32 = is32 && (v >= -128) && (v <= 127);
  }

  // XCD-aware map: 4 mb-blocks sharing one W strip land on one XCD (L2 reuse of W)
  const int bid = blockIdx.x;
  const int nb = (bid & 7) * 16 + ((bid >> 3) >> 2);
  const int mb = (bid >> 3) & 3;
  const int m0 = mb * BM;
  const int n0 = nb * BN;

  // --- x staging: 32 wave-instrs of 1 KiB via global_load_lds (dst = uniform base + lane*16)
  const unsigned short* xsrc[8];
  uint xdst[8];
#pragma unroll
  for (int j = 0; j < 8; ++j) {
    const int s = wid * 8 + j;           // 0..31
    const int plane = s >> 4;            // 0: hi, 1: lo
    const int sp = s & 15;
    const int rr = sp * 4 + (lane >> 4); // row in tile 0..63
    const int p = (lane & 15) ^ (rr & 15);  // fetch the chunk that belongs at LDS pos lane&15
    const unsigned short* base = plane ? xlo : xhi;
    xsrc[j] = base + (size_t)(m0 + rr) * K_IN + p * 8;
    xdst[j] = (uint)(plane * 16384 + sp * 1024);
  }

  // --- W staging descriptors
  // int32 path: 16 iters; chunkid = i*256+tid -> row = i*8 + (tid>>5), c32 = tid&31 (16B int32 chunks)
  const int trow = tid >> 5;
  const int c32 = tid & 31;
  const int wch = c32 >> 1;       // bf16 16B-chunk index (2 int32-chunks per bf16 chunk)
  const int whalf = c32 & 1;
  const int* w32base = wi + (size_t)(n0 + trow) * K_IN + c32 * 4;
  const uint w32lds = 32768u + (uint)(trow * 256) + (uint)((wch ^ trow) << 4) + (uint)(whalf * 8);
  // int8 path: 4 iters; chunkid = i*256+tid -> row = i*32 + (tid>>3), c8 = tid&7 (16B int8 chunks)
  const int r8 = tid >> 3;
  const int c8 = tid & 7;
  const signed char* w8base = wb + (size_t)(n0 + r8) * K_IN + c8 * 16;
  const uint w8lds = 32768u + (uint)(r8 * 256) + (uint)(((2 * c8) ^ (r8 & 15)) << 4);

  const int xorl = lane & 15;
  const int quad = lane >> 4;
  const int wm = (wid & 1) * 32;
  const int wn = (wid >> 1) * 64;

  v4f acc[2][4] = {};  // [mf][nf], shared by both planes

  for (int step = 0; step < NSTEPS; ++step) {
    __syncthreads();  // previous compute done; safe to overwrite buffer
#pragma unroll
    for (int j = 0; j < 8; ++j)
      __builtin_amdgcn_global_load_lds(
          (const __attribute__((address_space(1))) void*)(xsrc[j] + step * 128),
          (__attribute__((address_space(3))) void*)(smem + xdst[j]), 16, 0, 0);
    if (is32) {
#pragma unroll
      for (int i = 0; i < 16; ++i) {
        v4i t = *(const v4i*)(w32base + (size_t)i * 8 * K_IN + step * 128);
        uint2 d;
        d.x = bf16_trunc_bits((float)t.x) | (bf16_trunc_bits((float)t.y) << 16);
        d.y = bf16_trunc_bits((float)t.z) | (bf16_trunc_bits((float)t.w) << 16);
        // row = i*8+trow: +i*2048 is additive; (row&15) flips bit3 -> pos field XORs 128
        const uint a = (w32lds + (uint)(i * 2048)) ^ (uint)((i & 1) << 7);
        *(uint2*)(smem + a) = d;
      }
    } else {
#pragma unroll
      for (int i = 0; i < 4; ++i) {
        v4i t = *(const v4i*)(w8base + (size_t)i * 32 * K_IN + step * 128);
        const signed char* bs = (const signed char*)&t;
        uint u[8];
#pragma unroll
        for (int q = 0; q < 8; ++q)
          u[q] = bf16_trunc_bits((float)bs[2 * q]) |
                 (bf16_trunc_bits((float)bs[2 * q + 1]) << 16);
        const uint a = w8lds + (uint)(i * 8192);  // row += 32: additive, row&15 unchanged
        *(v4i*)(smem + a) = *(v4i*)&u[0];         // chunk 2c   at pos (2c)^r15
        *(v4i*)(smem + (a ^ 16u)) = *(v4i*)&u[4]; // chunk 2c+1 at pos^1 -> addr^16
      }
    }
    __syncthreads();  // publish (compiler drains vmcnt+lgkmcnt before s_barrier)

#pragma unroll
    for (int kc = 0; kc < 4; ++kc) {
      const uint cpos = (uint)(((kc * 4 + quad) ^ xorl) << 4);
      v8s ah[2], al[2], b[4];
#pragma unroll
      for (int mf = 0; mf < 2; ++mf) {
        const uint ra = (uint)((wm + mf * 16 + xorl) * 256) + cpos;
        ah[mf] = *(const v8s*)(smem + ra);
        al[mf] = *(const v8s*)(smem + 16384 + ra);
      }
#pragma unroll
      for (int nf = 0; nf < 4; ++nf) {
        const uint rb = (uint)((wn + nf * 16 + xorl) * 256) + cpos;
        b[nf] = *(const v8s*)(smem + 32768 + rb);
      }
#pragma unroll
      for (int mf = 0; mf < 2; ++mf)
#pragma unroll
        for (int nf = 0; nf < 4; ++nf) {
          acc[mf][nf] = __builtin_amdgcn_mfma_f32_16x16x32_bf16(ah[mf], b[nf], acc[mf][nf], 0, 0, 0);
          acc[mf][nf] = __builtin_amdgcn_mfma_f32_16x16x32_bf16(al[mf], b[nf], acc[mf][nf], 0, 0, 0);
        }
    }
  }

  // epilogue: verified 16x16 C/D layout: col = lane&15, row = quad*4 + reg
#pragma unroll
  for (int nf = 0; nf < 4; ++nf) {
    const int n = n0 + wn + nf * 16 + xorl;
    const float scl = scales[n];
#pragma unroll
    for (int mf = 0; mf < 2; ++mf)
#pragma unroll
      for (int reg = 0; reg < 4; ++reg) {
        const int m = m0 + wm + mf * 16 + quad * 4 + reg;
        out[(size_t)m * N_OUT + n] = acc[mf][nf][reg] * scl;
      }
  }
}

// ---------------- fallback (workspace too small); also dtype-probed ----------------
__global__ void naive_kernel(const float* __restrict__ x, const void* __restrict__ wraw,
                             const float* __restrict__ scales, float* __restrict__ out) {
  const int* wi = (const int*)wraw;
  bool is32 = true;
  for (int i = 0; i < 16; ++i) { int v = wi[i]; is32 = is32 && v >= -128 && v <= 127; }
  const int idx = blockIdx.x * 256 + threadIdx.x;
  const int m = idx >> 14;
  const int n = idx & (N_OUT - 1);
  const float* xr = x + (size_t)m * K_IN;
  float acc = 0.f;
  if (is32) {
    const int* wr = wi + (size_t)n * K_IN;
    for (int k = 0; k < K_IN; ++k) acc += xr[k] * (float)wr[k];
  } else {
    const signed char* wr = (const signed char*)wraw + (size_t)n * K_IN;
    for (int k = 0; k < K_IN; ++k) acc += xr[k] * (float)wr[k];
  }
  out[idx] = acc * scales[n];
}

extern "C" void kernel_launch(void* const* d_in, const int* in_sizes, int n_in,
                              void* d_out, int out_size, void* d_ws, size_t ws_size,
                              hipStream_t stream) {
  const float* x = (const float*)d_in[0];
  const void* w = d_in[1];  // dtype resolved on-device (int8 vs int32 materialization)
  const float* scales = (const float*)d_in[2];
  float* out = (float*)d_out;
  if (ws_size >= (size_t)4 * 1024 * 1024) {
    unsigned short* xhi = (unsigned short*)d_ws;
    unsigned short* xlo = xhi + (size_t)M_TOK * K_IN;
    cast_kernel<<<(M_TOK * K_IN) / 1024, 256, 0, stream>>>(x, xhi, xlo);
    gemm_kernel<<<512, 256, 0, stream>>>(xhi, xlo, w, scales, out);
  } else {
    naive_kernel<<<(M_TOK * N_OUT) / 256, 256, 0, stream>>>(x, w, scales, out);
  }
}